// Round 4
// baseline (200.399 us; speedup 1.0000x reference)
//
#include <hip/hip_runtime.h>
#include <math.h>

#define NCH    1024          // channels
#define NN     64            // nodes (8x8)
#define CK     32            // channels per staged chunk (fused fallback)
#define KSC    28.853900817779268f   // 20 * log2(e)  (exp(-cost/0.05) = 2^((sim-1)*KSC))
#define SPLIT  4             // records per batch in ws
#define WSB    4352          // floats per record: 4096 gram + 4*64 stats

// ===================== Kernel A4: async-staged Gram partials =====================
// grid = 512*SPLIT blocks x 256 threads (4 waves). Block (b,s); wave w owns
// channels [s*256 + w*64, +64) in 16 chunks of 4 channels. Staging is
// global_load_lds (16B) into a per-wave private double buffer; counted
// s_waitcnt vmcnt(2) keeps 2 chunks in flight; NO barriers in the main loop.
__global__ __launch_bounds__(256, 4)
void gram_stream(const float* __restrict__ proto,
                 const float* __restrict__ query,
                 float* __restrict__ ws)
{
    // per-wave staging: wave w at [w*1024], buffer k at [+k*512]: q 256 | p 256.
    // After streaming, the whole 4096-float region is reused as the gram merge buf.
    __shared__ __align__(16) float lds[4096];
    __shared__ __align__(16) float statd[4][NN];

    const int bid = blockIdx.x;
    const int b = bid >> 2, s = bid & 3;
    const int t = threadIdx.x;
    const int w = t >> 6;            // wave 0..3
    const int l = t & 63;            // lane
    const int r0 = (l >> 3) * 8;     // q-node rows owned (8)
    const int c0 = (l & 7) * 8;      // p-node cols owned (8)

    const float* __restrict__ qw = query + (size_t)b * (NCH * NN) + (s * 256 + w * 64) * NN;
    const float* __restrict__ pw = proto + (size_t)b * (NCH * NN) + (s * 256 + w * 64) * NN;

    float* const stg = &lds[w * 1024];

    float acc[8][8];
    #pragma unroll
    for (int i = 0; i < 8; ++i)
        #pragma unroll
        for (int j = 0; j < 8; ++j) acc[i][j] = 0.0f;
    float sqa[8] = {0,0,0,0,0,0,0,0}, q2a[8] = {0,0,0,0,0,0,0,0};
    float spb[8] = {0,0,0,0,0,0,0,0}, p2b[8] = {0,0,0,0,0,0,0,0};

#define ISSUE(CH) do {                                                          \
        const int kb_ = (CH) & 1;                                               \
        const float* gq_ = qw + (CH) * 256 + 4 * l;                             \
        const float* gp_ = pw + (CH) * 256 + 4 * l;                             \
        __builtin_amdgcn_global_load_lds(                                       \
            (const __attribute__((address_space(1))) void*)gq_,                 \
            (__attribute__((address_space(3))) void*)(stg + kb_ * 512), 16, 0, 0); \
        __builtin_amdgcn_global_load_lds(                                       \
            (const __attribute__((address_space(1))) void*)gp_,                 \
            (__attribute__((address_space(3))) void*)(stg + kb_ * 512 + 256), 16, 0, 0); \
    } while (0)

#define COMPUTE(CH) do {                                                        \
        const float* sq_ = stg + ((CH) & 1) * 512;                              \
        const float* sp_ = sq_ + 256;                                           \
        _Pragma("unroll")                                                       \
        for (int cc = 0; cc < 4; ++cc) {                                        \
            float4 a0 = *(const float4*)(sq_ + cc * 64 + r0);                   \
            float4 a1 = *(const float4*)(sq_ + cc * 64 + r0 + 4);               \
            float4 b0 = *(const float4*)(sp_ + cc * 64 + c0);                   \
            float4 b1 = *(const float4*)(sp_ + cc * 64 + c0 + 4);               \
            const float av[8] = {a0.x,a0.y,a0.z,a0.w,a1.x,a1.y,a1.z,a1.w};      \
            const float bv[8] = {b0.x,b0.y,b0.z,b0.w,b1.x,b1.y,b1.z,b1.w};      \
            _Pragma("unroll")                                                   \
            for (int i = 0; i < 8; ++i) {                                       \
                sqa[i] += av[i]; q2a[i] = fmaf(av[i], av[i], q2a[i]);           \
                spb[i] += bv[i]; p2b[i] = fmaf(bv[i], bv[i], p2b[i]);           \
            }                                                                   \
            _Pragma("unroll")                                                   \
            for (int i = 0; i < 8; ++i)                                         \
                _Pragma("unroll")                                               \
                for (int j = 0; j < 8; ++j)                                     \
                    acc[i][j] = fmaf(av[i], bv[j], acc[i][j]);                  \
        }                                                                       \
    } while (0)

    // prologue: 2 chunks in flight
    ISSUE(0);
    ISSUE(1);

    for (int ch = 0; ch < 15; ++ch) {
        asm volatile("s_waitcnt vmcnt(2)" ::: "memory");   // chunk ch landed; ch+1 in flight
        __builtin_amdgcn_sched_barrier(0);
        COMPUTE(ch);
        if (ch + 2 < 16) ISSUE(ch + 2);                    // refill the buffer just consumed
    }
    asm volatile("s_waitcnt vmcnt(0)" ::: "memory");
    __builtin_amdgcn_sched_barrier(0);
    COMPUTE(15);

    // ---------------- merge the 4 wave-partials (serialized, 3 barriers) ----------------
    __syncthreads();                 // all waves done with their staging regions

    float* __restrict__ wsb = ws + (size_t)bid * WSB;

    #pragma unroll 1
    for (int wv = 0; wv < 4; ++wv) {
        if (w == wv) {
            if (wv == 0) {
                #pragma unroll
                for (int i = 0; i < 8; ++i) {
                    float4 v0; v0.x=acc[i][0]; v0.y=acc[i][1]; v0.z=acc[i][2]; v0.w=acc[i][3];
                    float4 v1; v1.x=acc[i][4]; v1.y=acc[i][5]; v1.z=acc[i][6]; v1.w=acc[i][7];
                    *(float4*)&lds[(r0 + i) * 64 + c0]     = v0;
                    *(float4*)&lds[(r0 + i) * 64 + c0 + 4] = v1;
                }
                if ((l & 7) == 0) {
                    #pragma unroll
                    for (int i = 0; i < 8; ++i) { statd[0][r0 + i] = sqa[i]; statd[1][r0 + i] = q2a[i]; }
                }
                if (l < 8) {
                    #pragma unroll
                    for (int j = 0; j < 8; ++j) { statd[2][c0 + j] = spb[j]; statd[3][c0 + j] = p2b[j]; }
                }
            } else if (wv < 3) {
                #pragma unroll
                for (int i = 0; i < 8; ++i) {
                    float4 d0 = *(const float4*)&lds[(r0 + i) * 64 + c0];
                    float4 d1 = *(const float4*)&lds[(r0 + i) * 64 + c0 + 4];
                    d0.x+=acc[i][0]; d0.y+=acc[i][1]; d0.z+=acc[i][2]; d0.w+=acc[i][3];
                    d1.x+=acc[i][4]; d1.y+=acc[i][5]; d1.z+=acc[i][6]; d1.w+=acc[i][7];
                    *(float4*)&lds[(r0 + i) * 64 + c0]     = d0;
                    *(float4*)&lds[(r0 + i) * 64 + c0 + 4] = d1;
                }
                if ((l & 7) == 0) {
                    #pragma unroll
                    for (int i = 0; i < 8; ++i) { statd[0][r0 + i] += sqa[i]; statd[1][r0 + i] += q2a[i]; }
                }
                if (l < 8) {
                    #pragma unroll
                    for (int j = 0; j < 8; ++j) { statd[2][c0 + j] += spb[j]; statd[3][c0 + j] += p2b[j]; }
                }
            } else {                 // wv == 3: add own partial and write the record
                #pragma unroll
                for (int i = 0; i < 8; ++i) {
                    float4 d0 = *(const float4*)&lds[(r0 + i) * 64 + c0];
                    float4 d1 = *(const float4*)&lds[(r0 + i) * 64 + c0 + 4];
                    d0.x+=acc[i][0]; d0.y+=acc[i][1]; d0.z+=acc[i][2]; d0.w+=acc[i][3];
                    d1.x+=acc[i][4]; d1.y+=acc[i][5]; d1.z+=acc[i][6]; d1.w+=acc[i][7];
                    *(float4*)&wsb[(r0 + i) * 64 + c0]     = d0;
                    *(float4*)&wsb[(r0 + i) * 64 + c0 + 4] = d1;
                }
                if ((l & 7) == 0) {
                    #pragma unroll
                    for (int i = 0; i < 8; ++i) {
                        wsb[4096 +   0 + r0 + i] = statd[0][r0 + i] + sqa[i];
                        wsb[4096 +  64 + r0 + i] = statd[1][r0 + i] + q2a[i];
                    }
                }
                if (l < 8) {
                    #pragma unroll
                    for (int j = 0; j < 8; ++j) {
                        wsb[4096 + 128 + c0 + j] = statd[2][c0 + j] + spb[j];
                        wsb[4096 + 192 + c0 + j] = statd[3][c0 + j] + p2b[j];
                    }
                }
            }
        }
        if (wv < 3) __syncthreads();
    }
#undef ISSUE
#undef COMPUTE
}

#define DOT16(KK, ARR) ({ \
    float4 x0 = *(const float4*)&ARR[sp4*16 +  0]; \
    float4 x1 = *(const float4*)&ARR[sp4*16 +  4]; \
    float4 x2 = *(const float4*)&ARR[sp4*16 +  8]; \
    float4 x3 = *(const float4*)&ARR[sp4*16 + 12]; \
    float a0 = 0.0f, a1 = 0.0f; \
    a0=fmaf(KK[0],x0.x,a0);  a1=fmaf(KK[1],x0.y,a1); \
    a0=fmaf(KK[2],x0.z,a0);  a1=fmaf(KK[3],x0.w,a1); \
    a0=fmaf(KK[4],x1.x,a0);  a1=fmaf(KK[5],x1.y,a1); \
    a0=fmaf(KK[6],x1.z,a0);  a1=fmaf(KK[7],x1.w,a1); \
    a0=fmaf(KK[8],x2.x,a0);  a1=fmaf(KK[9],x2.y,a1); \
    a0=fmaf(KK[10],x2.z,a0); a1=fmaf(KK[11],x2.w,a1); \
    a0=fmaf(KK[12],x3.x,a0); a1=fmaf(KK[13],x3.y,a1); \
    a0=fmaf(KK[14],x3.z,a0); a1=fmaf(KK[15],x3.w,a1); \
    a0 + a1; })

// ===================== Kernel B: combine + sim + K + Sinkhorn + logits =====================
__global__ __launch_bounds__(256)
void emd_solve(const float* __restrict__ ws, float* __restrict__ out)
{
    __shared__ __align__(16) float stage[16 * 64];          // colsum partials
    __shared__ __align__(16) float Kl [NN][68];
    __shared__ __align__(16) float KTl[NN][68];
    __shared__ __align__(16) float statL[4][NN];
    __shared__ __align__(16) float uL[NN];
    __shared__ __align__(16) float vL[NN];
    __shared__ __align__(16) float rL[NN];
    __shared__ __align__(16) float cL[NN];
    __shared__ float redl[4];

    const int b  = blockIdx.x;
    const int t  = threadIdx.x;
    const int tr = t >> 4, tc = t & 15;
    const int n0 = tr * 4, m0 = tc * 4;

    const float* __restrict__ wsb = ws + (size_t)b * SPLIT * WSB;

    float acc[4][4];
    #pragma unroll
    for (int i = 0; i < 4; ++i)
        #pragma unroll
        for (int j = 0; j < 4; ++j) acc[i][j] = 0.0f;
    #pragma unroll
    for (int s = 0; s < SPLIT; ++s) {
        const float* __restrict__ g = wsb + s * WSB;
        #pragma unroll
        for (int i = 0; i < 4; ++i) {
            float4 v = *(const float4*)&g[(n0 + i) * 64 + m0];
            acc[i][0] += v.x; acc[i][1] += v.y; acc[i][2] += v.z; acc[i][3] += v.w;
        }
    }
    if (t < NN) {
        float s0 = 0, s1 = 0, s2 = 0, s3 = 0;
        #pragma unroll
        for (int s = 0; s < SPLIT; ++s) {
            const float* __restrict__ g = wsb + s * WSB + 4096;
            s0 += g[t]; s1 += g[64 + t]; s2 += g[128 + t]; s3 += g[192 + t];
        }
        statL[0][t] = s0; statL[1][t] = s1; statL[2][t] = s2; statL[3][t] = s3;
    }
    #pragma unroll
    for (int i = 0; i < 4; ++i) {
        float s = acc[i][0] + acc[i][1] + acc[i][2] + acc[i][3];
        s += __shfl_xor(s, 1, 64); s += __shfl_xor(s, 2, 64);
        s += __shfl_xor(s, 4, 64); s += __shfl_xor(s, 8, 64);
        if (tc == 0) uL[n0 + i] = s;
    }
    #pragma unroll
    for (int j = 0; j < 4; ++j)
        stage[tr * 64 + m0 + j] = acc[0][j] + acc[1][j] + acc[2][j] + acc[3][j];
    __syncthreads();

    if (t < NN) {
        float cs = 0;
        #pragma unroll
        for (int i = 0; i < 16; ++i) cs += stage[i * 64 + t];
        float w2 = fmaxf(cs * (1.0f/64.0f), 0.0f) + 0.001f;
        float w1 = fmaxf(uL[t] * (1.0f/64.0f), 0.0f) + 0.001f;
        float s1 = w1, s2 = w2;
        #pragma unroll
        for (int m = 1; m < 64; m <<= 1) {
            s1 += __shfl_xor(s1, m, 64);
            s2 += __shfl_xor(s2, m, 64);
        }
        rL[t] = w1 / s1;
        cL[t] = w2 / s2;
        vL[t] = 1.0f;
    }
    {
        float nq_[4], np_[4], sqn[4], spm[4];
        #pragma unroll
        for (int i = 0; i < 4; ++i) {
            float sv  = statL[0][n0 + i];
            float var = statL[1][n0 + i] - sv * sv * (1.0f/1024.0f);
            nq_[i] = fmaxf(sqrtf(fmaxf(var, 0.0f)), 1e-8f);
            sqn[i] = sv;
        }
        #pragma unroll
        for (int j = 0; j < 4; ++j) {
            float sv  = statL[2][m0 + j];
            float var = statL[3][m0 + j] - sv * sv * (1.0f/1024.0f);
            np_[j] = fmaxf(sqrtf(fmaxf(var, 0.0f)), 1e-8f);
            spm[j] = sv;
        }
        #pragma unroll
        for (int i = 0; i < 4; ++i) {
            #pragma unroll
            for (int j = 0; j < 4; ++j) {
                float sim = (acc[i][j] - sqn[i] * spm[j] * (1.0f/1024.0f)) / (nq_[i] * np_[j]);
                acc[i][j] = sim;
                float Kv = exp2f((sim - 1.0f) * KSC);
                Kl [n0 + i][m0 + j] = Kv;
                KTl[m0 + j][n0 + i] = Kv;
            }
        }
    }
    __syncthreads();

    const int sn  = t >> 2;
    const int sp4 = t & 3;
    float Kr[16], KTr[16];
    #pragma unroll
    for (int jj = 0; jj < 4; ++jj) {
        float4 kv = *(const float4*)&Kl [sn][sp4 * 16 + jj * 4];
        float4 kt = *(const float4*)&KTl[sn][sp4 * 16 + jj * 4];
        Kr [jj*4+0]=kv.x; Kr [jj*4+1]=kv.y; Kr [jj*4+2]=kv.z; Kr [jj*4+3]=kv.w;
        KTr[jj*4+0]=kt.x; KTr[jj*4+1]=kt.y; KTr[jj*4+2]=kt.z; KTr[jj*4+3]=kt.w;
    }
    const float rreg = rL[sn];
    const float creg = cL[sn];

    for (int it = 0; it < 100; ++it) {
        float s = DOT16(Kr, vL);
        s += __shfl_xor(s, 1, 64); s += __shfl_xor(s, 2, 64);
        float u = rreg / fmaxf(s, 1e-30f);
        if (sp4 == 0) uL[sn] = u;
        __syncthreads();
        float s2 = DOT16(KTr, uL);
        s2 += __shfl_xor(s2, 1, 64); s2 += __shfl_xor(s2, 2, 64);
        float vv = creg / fmaxf(s2, 1e-30f);
        if (sp4 == 0) vL[sn] = vv;
        __syncthreads();
    }
    {
        float s = DOT16(Kr, vL);
        s += __shfl_xor(s, 1, 64); s += __shfl_xor(s, 2, 64);
        float u = rreg / fmaxf(s, 1e-30f);
        if (sp4 == 0) uL[sn] = u;
    }
    __syncthreads();

    float uu[4], vv_[4];
    #pragma unroll
    for (int i = 0; i < 4; ++i) uu[i]  = uL[n0 + i];
    #pragma unroll
    for (int j = 0; j < 4; ++j) vv_[j] = vL[m0 + j];
    float part = 0.0f;
    #pragma unroll
    for (int i = 0; i < 4; ++i) {
        #pragma unroll
        for (int j = 0; j < 4; ++j) {
            float sim = acc[i][j];
            float Kv  = exp2f((sim - 1.0f) * KSC);
            part = fmaf(sim * Kv, uu[i] * vv_[j], part);
        }
    }
    #pragma unroll
    for (int m = 1; m < 64; m <<= 1) part += __shfl_xor(part, m, 64);
    if ((t & 63) == 0) redl[t >> 6] = part;
    __syncthreads();
    if (t == 0) out[b] = (redl[0] + redl[1] + redl[2] + redl[3]) * (12.5f / 64.0f);
}

// ===================== Fallback: verified fused single-kernel path =====================
#define STAT_Q(v) { sqp[0]+=(v).x; q2p[0]=fmaf((v).x,(v).x,q2p[0]); \
                    sqp[1]+=(v).y; q2p[1]=fmaf((v).y,(v).y,q2p[1]); \
                    sqp[2]+=(v).z; q2p[2]=fmaf((v).z,(v).z,q2p[2]); \
                    sqp[3]+=(v).w; q2p[3]=fmaf((v).w,(v).w,q2p[3]); }
#define STAT_P(v) { spp[0]+=(v).x; p2p[0]=fmaf((v).x,(v).x,p2p[0]); \
                    spp[1]+=(v).y; p2p[1]=fmaf((v).y,(v).y,p2p[1]); \
                    spp[2]+=(v).z; p2p[2]=fmaf((v).z,(v).z,p2p[2]); \
                    spp[3]+=(v).w; p2p[3]=fmaf((v).w,(v).w,p2p[3]); }

#define GRAM_CHUNK_BODY(NCHUNK_, QB_, PB_)                                     \
    for (int ch = 0; ch < (NCHUNK_); ++ch) {                                   \
        if (ch) __syncthreads();                                               \
        *(float4*)&stage[       ofs] = qv0;                                    \
        *(float4*)&stage[1024 + ofs] = qv1;                                    \
        *(float4*)&stage[2048 + ofs] = pv0;                                    \
        *(float4*)&stage[3072 + ofs] = pv1;                                    \
        float4 nq0, nq1, np0, np1;                                             \
        const bool more = (ch + 1 < (NCHUNK_));                                \
        if (more) {                                                            \
            const float* qn = (QB_) + (ch + 1) * 2048;                         \
            const float* pn = (PB_) + (ch + 1) * 2048;                         \
            nq0 = *(const float4*)(qn + ofs);                                  \
            nq1 = *(const float4*)(qn + 1024 + ofs);                           \
            np0 = *(const float4*)(pn + ofs);                                  \
            np1 = *(const float4*)(pn + 1024 + ofs);                           \
        }                                                                      \
        STAT_Q(qv0); STAT_Q(qv1);                                              \
        STAT_P(pv0); STAT_P(pv1);                                              \
        __syncthreads();                                                       \
        _Pragma("unroll 8")                                                    \
        for (int cc = 0; cc < CK; ++cc) {                                      \
            float4 a  = *(const float4*)&stage[cc * 64 + n0];                  \
            float4 bb = *(const float4*)&stage[2048 + cc * 64 + m0];           \
            acc[0][0]=fmaf(a.x,bb.x,acc[0][0]); acc[0][1]=fmaf(a.x,bb.y,acc[0][1]); \
            acc[0][2]=fmaf(a.x,bb.z,acc[0][2]); acc[0][3]=fmaf(a.x,bb.w,acc[0][3]); \
            acc[1][0]=fmaf(a.y,bb.x,acc[1][0]); acc[1][1]=fmaf(a.y,bb.y,acc[1][1]); \
            acc[1][2]=fmaf(a.y,bb.z,acc[1][2]); acc[1][3]=fmaf(a.y,bb.w,acc[1][3]); \
            acc[2][0]=fmaf(a.z,bb.x,acc[2][0]); acc[2][1]=fmaf(a.z,bb.y,acc[2][1]); \
            acc[2][2]=fmaf(a.z,bb.z,acc[2][2]); acc[2][3]=fmaf(a.z,bb.w,acc[2][3]); \
            acc[3][0]=fmaf(a.w,bb.x,acc[3][0]); acc[3][1]=fmaf(a.w,bb.y,acc[3][1]); \
            acc[3][2]=fmaf(a.w,bb.z,acc[3][2]); acc[3][3]=fmaf(a.w,bb.w,acc[3][3]); \
        }                                                                      \
        if (more) { qv0 = nq0; qv1 = nq1; pv0 = np0; pv1 = np1; }              \
    }

__global__ __launch_bounds__(256)
void deepemd_fused(const float* __restrict__ proto,
                   const float* __restrict__ query,
                   float* __restrict__ out)
{
    __shared__ __align__(16) float stage[2 * CK * NN];
    __shared__ __align__(16) float Kl [NN][68];
    __shared__ __align__(16) float KTl[NN][68];
    __shared__ __align__(16) float statL[4][NN];
    __shared__ __align__(16) float uL[NN];
    __shared__ __align__(16) float vL[NN];
    __shared__ __align__(16) float rL[NN];
    __shared__ __align__(16) float cL[NN];
    __shared__ float redl[4];

    const int b  = blockIdx.x;
    const int t  = threadIdx.x;
    const int tr = t >> 4, tc = t & 15;
    const int n0 = tr * 4, m0 = tc * 4;
    const int ofs = 4 * t;

    const float* __restrict__ pb = proto + (size_t)b * (NCH * NN);
    const float* __restrict__ qb = query + (size_t)b * (NCH * NN);

    float acc[4][4];
    #pragma unroll
    for (int i = 0; i < 4; ++i)
        #pragma unroll
        for (int j = 0; j < 4; ++j) acc[i][j] = 0.0f;
    float sqp[4] = {0,0,0,0}, q2p[4] = {0,0,0,0};
    float spp[4] = {0,0,0,0}, p2p[4] = {0,0,0,0};

    float4 qv0 = *(const float4*)(qb + ofs);
    float4 qv1 = *(const float4*)(qb + 1024 + ofs);
    float4 pv0 = *(const float4*)(pb + ofs);
    float4 pv1 = *(const float4*)(pb + 1024 + ofs);

    GRAM_CHUNK_BODY(NCH / CK, qb, pb)
    __syncthreads();

    #pragma unroll
    for (int i = 0; i < 4; ++i) {
        float s = acc[i][0] + acc[i][1] + acc[i][2] + acc[i][3];
        s += __shfl_xor(s, 1, 64); s += __shfl_xor(s, 2, 64);
        s += __shfl_xor(s, 4, 64); s += __shfl_xor(s, 8, 64);
        if (tc == 0) uL[n0 + i] = s;
    }
    #pragma unroll
    for (int k = 0; k < 4; ++k) {
        stage[t*16 +      k] = sqp[k];
        stage[t*16 +  4 + k] = q2p[k];
        stage[t*16 +  8 + k] = spp[k];
        stage[t*16 + 12 + k] = p2p[k];
    }
    __syncthreads();
    if (t < NN) {
        const int g = t >> 2, k = t & 3;
        float ssq = 0, sq2 = 0, ssp = 0, sp2 = 0;
        #pragma unroll
        for (int j = 0; j < 16; ++j) {
            const float* row = &stage[(j * 16 + g) * 16];
            ssq += row[k]; sq2 += row[4 + k]; ssp += row[8 + k]; sp2 += row[12 + k];
        }
        statL[0][t] = ssq; statL[1][t] = sq2; statL[2][t] = ssp; statL[3][t] = sp2;
    }
    __syncthreads();
    #pragma unroll
    for (int j = 0; j < 4; ++j)
        stage[tr * 64 + m0 + j] = acc[0][j] + acc[1][j] + acc[2][j] + acc[3][j];
    __syncthreads();
    if (t < NN) {
        float cs = 0;
        #pragma unroll
        for (int i = 0; i < 16; ++i) cs += stage[i * 64 + t];
        float w2 = fmaxf(cs * (1.0f/64.0f), 0.0f) + 0.001f;
        float w1 = fmaxf(uL[t] * (1.0f/64.0f), 0.0f) + 0.001f;
        float s1 = w1, s2 = w2;
        #pragma unroll
        for (int m = 1; m < 64; m <<= 1) {
            s1 += __shfl_xor(s1, m, 64);
            s2 += __shfl_xor(s2, m, 64);
        }
        rL[t] = w1 / s1;
        cL[t] = w2 / s2;
        vL[t] = 1.0f;
    }
    __syncthreads();

    {
        float nq_[4], np_[4], sqn[4], spm[4];
        #pragma unroll
        for (int i = 0; i < 4; ++i) {
            float sv  = statL[0][n0 + i];
            float var = statL[1][n0 + i] - sv * sv * (1.0f/1024.0f);
            nq_[i] = fmaxf(sqrtf(fmaxf(var, 0.0f)), 1e-8f);
            sqn[i] = sv;
        }
        #pragma unroll
        for (int j = 0; j < 4; ++j) {
            float sv  = statL[2][m0 + j];
            float var = statL[3][m0 + j] - sv * sv * (1.0f/1024.0f);
            np_[j] = fmaxf(sqrtf(fmaxf(var, 0.0f)), 1e-8f);
            spm[j] = sv;
        }
        #pragma unroll
        for (int i = 0; i < 4; ++i) {
            #pragma unroll
            for (int j = 0; j < 4; ++j) {
                float sim = (acc[i][j] - sqn[i] * spm[j] * (1.0f/1024.0f)) / (nq_[i] * np_[j]);
                acc[i][j] = sim;
                float Kv = exp2f((sim - 1.0f) * KSC);
                Kl [n0 + i][m0 + j] = Kv;
                KTl[m0 + j][n0 + i] = Kv;
            }
        }
    }
    __syncthreads();

    const int sn  = t >> 2;
    const int sp4 = t & 3;
    float Kr[16], KTr[16];
    #pragma unroll
    for (int jj = 0; jj < 4; ++jj) {
        float4 kv = *(const float4*)&Kl [sn][sp4 * 16 + jj * 4];
        float4 kt = *(const float4*)&KTl[sn][sp4 * 16 + jj * 4];
        Kr [jj*4+0]=kv.x; Kr [jj*4+1]=kv.y; Kr [jj*4+2]=kv.z; Kr [jj*4+3]=kv.w;
        KTr[jj*4+0]=kt.x; KTr[jj*4+1]=kt.y; KTr[jj*4+2]=kt.z; KTr[jj*4+3]=kt.w;
    }
    const float rreg = rL[sn];
    const float creg = cL[sn];

    for (int it = 0; it < 100; ++it) {
        float s = DOT16(Kr, vL);
        s += __shfl_xor(s, 1, 64); s += __shfl_xor(s, 2, 64);
        float u = rreg / fmaxf(s, 1e-30f);
        if (sp4 == 0) uL[sn] = u;
        __syncthreads();
        float s2 = DOT16(KTr, uL);
        s2 += __shfl_xor(s2, 1, 64); s2 += __shfl_xor(s2, 2, 64);
        float vv = creg / fmaxf(s2, 1e-30f);
        if (sp4 == 0) vL[sn] = vv;
        __syncthreads();
    }
    {
        float s = DOT16(Kr, vL);
        s += __shfl_xor(s, 1, 64); s += __shfl_xor(s, 2, 64);
        float u = rreg / fmaxf(s, 1e-30f);
        if (sp4 == 0) uL[sn] = u;
    }
    __syncthreads();

    float uu[4], vv_[4];
    #pragma unroll
    for (int i = 0; i < 4; ++i) uu[i]  = uL[n0 + i];
    #pragma unroll
    for (int j = 0; j < 4; ++j) vv_[j] = vL[m0 + j];
    float part = 0.0f;
    #pragma unroll
    for (int i = 0; i < 4; ++i) {
        #pragma unroll
        for (int j = 0; j < 4; ++j) {
            float sim = acc[i][j];
            float Kv  = exp2f((sim - 1.0f) * KSC);
            part = fmaf(sim * Kv, uu[i] * vv_[j], part);
        }
    }
    #pragma unroll
    for (int m = 1; m < 64; m <<= 1) part += __shfl_xor(part, m, 64);
    if ((t & 63) == 0) redl[t >> 6] = part;
    __syncthreads();
    if (t == 0) out[b] = (redl[0] + redl[1] + redl[2] + redl[3]) * (12.5f / 64.0f);
}

extern "C" void kernel_launch(void* const* d_in, const int* in_sizes, int n_in,
                              void* d_out, int out_size, void* d_ws, size_t ws_size,
                              hipStream_t stream) {
    const float* proto = (const float*)d_in[0];
    const float* query = (const float*)d_in[1];
    float* out = (float*)d_out;
    (void)in_sizes; (void)n_in; (void)out_size;

    const size_t need = (size_t)512 * SPLIT * WSB * sizeof(float);   // ~35.7 MB
    if (ws_size >= need) {
        gram_stream<<<dim3(512 * SPLIT), dim3(256), 0, stream>>>(proto, query, (float*)d_ws);
        emd_solve  <<<dim3(512),         dim3(256), 0, stream>>>((const float*)d_ws, out);
    } else {
        deepemd_fused<<<dim3(512), dim3(256), 0, stream>>>(proto, query, out);
    }
}

// Round 5
// 150.364 us; speedup vs baseline: 1.3328x; 1.3328x over previous
//
#include <hip/hip_runtime.h>
#include <math.h>

#define NN  64
#define KSC 28.853900817779268f   // 20 * log2(e): exp(-cost/0.05) = 2^((sim-1)*KSC)

#define DOT16(KK, ARR) ({ \
    float4 x0 = *(const float4*)&ARR[sp4*16 +  0]; \
    float4 x1 = *(const float4*)&ARR[sp4*16 +  4]; \
    float4 x2 = *(const float4*)&ARR[sp4*16 +  8]; \
    float4 x3 = *(const float4*)&ARR[sp4*16 + 12]; \
    float a0 = 0.0f, a1 = 0.0f; \
    a0=fmaf(KK[0],x0.x,a0);  a1=fmaf(KK[1],x0.y,a1); \
    a0=fmaf(KK[2],x0.z,a0);  a1=fmaf(KK[3],x0.w,a1); \
    a0=fmaf(KK[4],x1.x,a0);  a1=fmaf(KK[5],x1.y,a1); \
    a0=fmaf(KK[6],x1.z,a0);  a1=fmaf(KK[7],x1.w,a1); \
    a0=fmaf(KK[8],x2.x,a0);  a1=fmaf(KK[9],x2.y,a1); \
    a0=fmaf(KK[10],x2.z,a0); a1=fmaf(KK[11],x2.w,a1); \
    a0=fmaf(KK[12],x3.x,a0); a1=fmaf(KK[13],x3.y,a1); \
    a0=fmaf(KK[14],x3.z,a0); a1=fmaf(KK[15],x3.w,a1); \
    a0 + a1; })

// One block per batch. 512 threads = 8 waves. Stream phase: each wave owns 128
// channels, reads q/p DIRECTLY from global (intra-wave broadcast, no LDS, no
// barriers), accumulating an 8x8 Gram tile per lane + per-node stats. Then:
// LDS merge -> sim/K -> Sinkhorn (verified math) -> logits.
__global__ __launch_bounds__(512, 4)
void deepemd_one(const float* __restrict__ proto,
                 const float* __restrict__ query,
                 float* __restrict__ out)
{
    __shared__ __align__(16) char smem[62464];
    float* const GA    = (float*)(smem);            // [64][64] final raw Gram
    float* const GB    = (float*)(smem + 16384);    // [64][64] waves 4-7 partial (dead after combine)
    float* const Kl    = (float*)(smem + 16384);    // [64][68] aliases GB (written after GB dies)
    float* const KTl   = (float*)(smem + 33792);    // [64][68]
    float* const st8   = (float*)(smem + 51200);    // [4][8][64] per-wave stats (dead after stL)
    float* const cs8   = (float*)(smem + 51200);    // [8][64] colsum partials (aliases st8)
    float* const stL   = (float*)(smem + 59392);    // [4][64] merged stats
    float* const uL    = (float*)(smem + 60416);    // [64]
    float* const vL    = (float*)(smem + 60672);    // [64]
    float* const rL    = (float*)(smem + 60928);    // [64]
    float* const cLm   = (float*)(smem + 61184);    // [64]
    float* const rowsum= (float*)(smem + 61440);    // [64]
    float* const redl  = (float*)(smem + 61696);    // [8]

    const int b  = blockIdx.x;
    const int t  = threadIdx.x;
    const int w  = t >> 6;           // wave 0..7
    const int l  = t & 63;           // lane
    const int ri = l >> 3;           // row-group 0..7
    const int ci = l & 7;            // col-group 0..7
    const int r0 = ri * 8;           // q-node rows owned: r0..r0+7
    const int c0 = ci * 4;           // p-node cols owned: c0..c0+3 and c0+32..c0+35

    const float* __restrict__ qw = query + (size_t)b * 65536 + w * 8192;
    const float* __restrict__ pw = proto + (size_t)b * 65536 + w * 8192;

    float acc[8][8];
    #pragma unroll
    for (int i = 0; i < 8; ++i)
        #pragma unroll
        for (int j = 0; j < 8; ++j) acc[i][j] = 0.0f;
    float sq = 0.0f, q2 = 0.0f, sp = 0.0f, p2 = 0.0f;

    // ---------------- stream: direct-global Gram, no LDS, no barriers ----------------
    #pragma unroll 2
    for (int c = 0; c < 128; ++c) {
        const float* qc = qw + c * 64;
        const float* pc = pw + c * 64;
        float4 a0 = *(const float4*)(qc + r0);
        float4 a1 = *(const float4*)(qc + r0 + 4);
        float4 b0 = *(const float4*)(pc + c0);
        float4 b1 = *(const float4*)(pc + c0 + 32);
        float  qs = qc[l];
        float  ps = pc[l];
        sq += qs; q2 = fmaf(qs, qs, q2);
        sp += ps; p2 = fmaf(ps, ps, p2);
        const float av[8] = {a0.x,a0.y,a0.z,a0.w,a1.x,a1.y,a1.z,a1.w};
        const float bv[8] = {b0.x,b0.y,b0.z,b0.w,b1.x,b1.y,b1.z,b1.w};
        #pragma unroll
        for (int i = 0; i < 8; ++i)
            #pragma unroll
            for (int j = 0; j < 8; ++j)
                acc[i][j] = fmaf(av[i], bv[j], acc[i][j]);
    }

    // per-node stats: lane l holds node l's stats for this wave's 128 channels
    st8[(0*8 + w)*64 + l] = sq;
    st8[(1*8 + w)*64 + l] = q2;
    st8[(2*8 + w)*64 + l] = sp;
    st8[(3*8 + w)*64 + l] = p2;

    // ---------------- merge Gram: waves 0-3 -> GA, waves 4-7 -> GB ----------------
    {
        float* const GT = (w < 4) ? GA : GB;
        const int wp = w & 3;
        #pragma unroll 1
        for (int p = 0; p < 4; ++p) {
            if (wp == p) {
                #pragma unroll
                for (int i = 0; i < 8; ++i) {
                    float4 v0; v0.x=acc[i][0]; v0.y=acc[i][1]; v0.z=acc[i][2]; v0.w=acc[i][3];
                    float4 v1; v1.x=acc[i][4]; v1.y=acc[i][5]; v1.z=acc[i][6]; v1.w=acc[i][7];
                    float* g0 = &GT[(r0 + i) * 64 + c0];
                    float* g1 = &GT[(r0 + i) * 64 + c0 + 32];
                    if (p == 0) {
                        *(float4*)g0 = v0;
                        *(float4*)g1 = v1;
                    } else {
                        float4 d0 = *(const float4*)g0;
                        float4 d1 = *(const float4*)g1;
                        d0.x+=v0.x; d0.y+=v0.y; d0.z+=v0.z; d0.w+=v0.w;
                        d1.x+=v1.x; d1.y+=v1.y; d1.z+=v1.z; d1.w+=v1.w;
                        *(float4*)g0 = d0;
                        *(float4*)g1 = d1;
                    }
                }
            }
            __syncthreads();
        }
    }

    // ---------------- combine GA += GB; merge stats ----------------
    {
        float4* ga = (float4*)&GA[t * 8];
        float4* gb = (float4*)&GB[t * 8];
        float4 x0 = ga[0], x1 = ga[1];
        float4 y0 = gb[0], y1 = gb[1];
        x0.x+=y0.x; x0.y+=y0.y; x0.z+=y0.z; x0.w+=y0.w;
        x1.x+=y1.x; x1.y+=y1.y; x1.z+=y1.z; x1.w+=y1.w;
        ga[0] = x0; ga[1] = x1;
    }
    if (t < NN) {
        #pragma unroll
        for (int k = 0; k < 4; ++k) {
            float s = 0.0f;
            #pragma unroll
            for (int w8 = 0; w8 < 8; ++w8) s += st8[(k*8 + w8)*64 + t];
            stL[k*64 + t] = s;
        }
        vL[t] = 1.0f;
    }
    __syncthreads();

    // ---------------- sim + K + raw row/col sums ----------------
    const int rr  = t >> 3;          // 0..63
    const int cc0 = (t & 7) * 8;     // 0..56
    float g[8], s_[8];
    *(float4*)&g[0] = *(const float4*)&GA[rr*64 + cc0];
    *(float4*)&g[4] = *(const float4*)&GA[rr*64 + cc0 + 4];

    {   // raw rowsum (weight_1): reduce across the 8 threads sharing rr
        float rs = ((g[0]+g[1])+(g[2]+g[3])) + ((g[4]+g[5])+(g[6]+g[7]));
        rs += __shfl_xor(rs, 1, 64); rs += __shfl_xor(rs, 2, 64); rs += __shfl_xor(rs, 4, 64);
        if ((t & 7) == 0) rowsum[rr] = rs;
    }
    {   // raw colsum partials: reduce across the 8 row-groups within this wave
        float cs_[8];
        #pragma unroll
        for (int j = 0; j < 8; ++j) {
            float v = g[j];
            v += __shfl_xor(v, 8, 64); v += __shfl_xor(v, 16, 64); v += __shfl_xor(v, 32, 64);
            cs_[j] = v;
        }
        if (l < 8) {
            #pragma unroll
            for (int j = 0; j < 8; ++j) cs8[w*64 + l*8 + j] = cs_[j];
        }
    }
    {   // sim (kept in regs) + K, K^T
        float sqn = stL[0*64 + rr];
        float q2n = stL[1*64 + rr];
        float var = q2n - sqn * sqn * (1.0f/1024.0f);
        float nq  = fmaxf(sqrtf(fmaxf(var, 0.0f)), 1e-8f);
        #pragma unroll
        for (int j = 0; j < 8; ++j) {
            float spm = stL[2*64 + cc0 + j];
            float p2m = stL[3*64 + cc0 + j];
            float varm = p2m - spm * spm * (1.0f/1024.0f);
            float np  = fmaxf(sqrtf(fmaxf(varm, 0.0f)), 1e-8f);
            float sim = (g[j] - sqn * spm * (1.0f/1024.0f)) / (nq * np);
            s_[j] = sim;
            float Kv = exp2f((sim - 1.0f) * KSC);
            Kl [rr*68 + cc0 + j] = Kv;
            KTl[(cc0 + j)*68 + rr] = Kv;
        }
    }
    __syncthreads();

    // ---------------- weights -> marginals ----------------
    if (t < NN) {
        float cs = 0.0f;
        #pragma unroll
        for (int w8 = 0; w8 < 8; ++w8) cs += cs8[w8*64 + t];
        float w2 = fmaxf(cs * (1.0f/64.0f), 0.0f) + 0.001f;
        float w1 = fmaxf(rowsum[t] * (1.0f/64.0f), 0.0f) + 0.001f;
        float s1 = w1, s2 = w2;
        #pragma unroll
        for (int m = 1; m < 64; m <<= 1) {
            s1 += __shfl_xor(s1, m, 64);
            s2 += __shfl_xor(s2, m, 64);
        }
        rL[t]  = w1 / s1;
        cLm[t] = w2 / s2;
    }
    __syncthreads();

    // ---------------- Sinkhorn: 4 threads per row, duplicated across wave halves ----------------
    const int sn  = (t & 255) >> 2;  // 0..63
    const int sp4 = t & 3;
    float Kr[16], KTr[16];
    #pragma unroll
    for (int jj = 0; jj < 4; ++jj) {
        float4 kv = *(const float4*)&Kl [sn*68 + sp4*16 + jj*4];
        float4 kt = *(const float4*)&KTl[sn*68 + sp4*16 + jj*4];
        Kr [jj*4+0]=kv.x; Kr [jj*4+1]=kv.y; Kr [jj*4+2]=kv.z; Kr [jj*4+3]=kv.w;
        KTr[jj*4+0]=kt.x; KTr[jj*4+1]=kt.y; KTr[jj*4+2]=kt.z; KTr[jj*4+3]=kt.w;
    }
    const float rreg = rL[sn];
    const float creg = cLm[sn];

    for (int it = 0; it < 100; ++it) {
        float s = DOT16(Kr, vL);
        s += __shfl_xor(s, 1, 64); s += __shfl_xor(s, 2, 64);
        float u = rreg / fmaxf(s, 1e-30f);
        if (sp4 == 0) uL[sn] = u;
        __syncthreads();
        float s2 = DOT16(KTr, uL);
        s2 += __shfl_xor(s2, 1, 64); s2 += __shfl_xor(s2, 2, 64);
        float vv = creg / fmaxf(s2, 1e-30f);
        if (sp4 == 0) vL[sn] = vv;
        __syncthreads();
    }
    {
        float s = DOT16(Kr, vL);
        s += __shfl_xor(s, 1, 64); s += __shfl_xor(s, 2, 64);
        float u = rreg / fmaxf(s, 1e-30f);
        if (sp4 == 0) uL[sn] = u;
    }
    __syncthreads();

    // ---------------- logits = sum(sim * u*K*v) * (T / N) ----------------
    {
        float uu = uL[rr];
        float part = 0.0f;
        #pragma unroll
        for (int j = 0; j < 8; ++j) {
            float Kv = Kl[rr*68 + cc0 + j];
            part = fmaf(s_[j] * Kv, uu * vL[cc0 + j], part);
        }
        #pragma unroll
        for (int m = 1; m < 64; m <<= 1) part += __shfl_xor(part, m, 64);
        if (l == 0) redl[w] = part;
    }
    __syncthreads();
    if (t == 0) {
        float tot = ((redl[0]+redl[1])+(redl[2]+redl[3]))
                  + ((redl[4]+redl[5])+(redl[6]+redl[7]));
        out[b] = tot * (12.5f / 64.0f);
    }
}

extern "C" void kernel_launch(void* const* d_in, const int* in_sizes, int n_in,
                              void* d_out, int out_size, void* d_ws, size_t ws_size,
                              hipStream_t stream) {
    const float* proto = (const float*)d_in[0];
    const float* query = (const float*)d_in[1];
    float* out = (float*)d_out;
    (void)in_sizes; (void)n_in; (void)d_ws; (void)ws_size; (void)out_size;
    deepemd_one<<<dim3(512), dim3(512), 0, stream>>>(proto, query, out);
}